// Round 2
// baseline (116.291 us; speedup 1.0000x reference)
//
#include <hip/hip_runtime.h>
#include <hip/hip_fp16.h>
#include <array>

// Problem constants (reference: H=64, M=N=128, k=9, w=3)
constexpr int HZ   = 64;
constexpr int NN   = 128;
constexpr int P    = HZ * NN * NN;    // 1,048,576 voxels
constexpr int KSEL = 9;
constexpr int NCOL = 27;              // 3x3x3 window

typedef _Float16 f16x2 __attribute__((ext_vector_type(2)));

constexpr int TY = 10;   // 8 core + 2 halo
constexpr int TX = 34;   // 32 core + 2 halo
constexpr int TROWS = 3 * TY * TX;   // 1020 tile rows (3 z-planes)

// ---------------------------------------------------------------------------
// Batcher merge-exchange network for n=27 + backward dead-CE pruning.
// ---------------------------------------------------------------------------
constexpr int compute_nce(int n) {
  int t = 0; while ((1 << t) < n) ++t;
  int cnt = 0;
  for (int p = 1 << (t - 1); p > 0; p >>= 1) {
    int q = 1 << (t - 1), r = 0, d = p;
    while (true) {
      for (int i = 0; i < n - d; ++i)
        if ((i & p) == r) ++cnt;
      if (q == p) break;
      d = q - p; r = p; q >>= 1;
    }
  }
  return cnt;
}
constexpr int NCE_FULL = compute_nce(NCOL);   // 155

struct CEPair { unsigned char a, b; };
constexpr std::array<CEPair, NCE_FULL> make_net() {
  std::array<CEPair, NCE_FULL> net{};
  int t = 0; while ((1 << t) < NCOL) ++t;
  int k = 0;
  for (int p = 1 << (t - 1); p > 0; p >>= 1) {
    int q = 1 << (t - 1), r = 0, d = p;
    while (true) {
      for (int i = 0; i < NCOL - d; ++i)
        if ((i & p) == r) {
          net[k].a = (unsigned char)i;
          net[k].b = (unsigned char)(i + d);
          ++k;
        }
      if (q == p) break;
      d = q - p; r = p; q >>= 1;
    }
  }
  return net;
}
constexpr auto FULLNET = make_net();

constexpr int count_pruned() {
  bool needed[NCOL] = {};
  for (int i = 0; i < KSEL; ++i) needed[i] = true;
  int cnt = 0;
  for (int e = NCE_FULL - 1; e >= 0; --e) {
    const int a = FULLNET[e].a, b = FULLNET[e].b;
    if (needed[a] || needed[b]) { needed[a] = true; needed[b] = true; ++cnt; }
  }
  return cnt;
}
constexpr int NCE = count_pruned();

constexpr std::array<CEPair, NCE> make_pruned() {
  bool needed[NCOL] = {};
  for (int i = 0; i < KSEL; ++i) needed[i] = true;
  std::array<bool, NCE_FULL> keep{};
  for (int e = NCE_FULL - 1; e >= 0; --e) {
    const int a = FULLNET[e].a, b = FULLNET[e].b;
    if (needed[a] || needed[b]) { keep[e] = true; needed[a] = true; needed[b] = true; }
  }
  std::array<CEPair, NCE> out{};
  int k = 0;
  for (int e = 0; e < NCE_FULL; ++e) if (keep[e]) out[k++] = FULLNET[e];
  return out;
}
constexpr auto NET = make_pruned();

// ---------------------------------------------------------------------------
// Async global->LDS DMA helper (pass 1 input staging only).
// ---------------------------------------------------------------------------
typedef const __attribute__((address_space(1))) unsigned GU;
typedef __attribute__((address_space(3))) unsigned LU;

__device__ __forceinline__ void g2l4(const void* g, void* l) {
  __builtin_amdgcn_global_load_lds((GU*)g, (LU*)l, 4, 0, 0);
}

// ---------------------------------------------------------------------------
// Pass 1: key = db<<32 | col<<27 | vbits>>5 (63 bits, sign bit 0).
// IEEE order == unsigned order for non-negative doubles, so each CE is
// v_min_f64 + v_max_f64. Order = (db, col) exactly -> exact stable order.
// Row output (SoA, 26 B/voxel total):
//   rowsA[vb]   = uint4  : halves h0..h7           (gathered by pass 2)
//   rowsB0h[vb] = ushort : h8                      (gathered by pass 2)
//   rowsC[vb]   = uint2  : {lo_cols30, hi_cols15}  (owner-read only)
// All stores are direct, per-thread, fully coalesced.
// ---------------------------------------------------------------------------
__global__ __launch_bounds__(256) void topk10(
    const float* __restrict__ anat,
    uint4* __restrict__ rowsA,
    unsigned short* __restrict__ rowsB0h,
    uint2* __restrict__ rowsC) {
  __shared__ float in_t[TROWS];   // 4.08 KB input halo
  const int tid = threadIdx.x;

  const int blk = blockIdx.x;
  const int swz = ((blk & 7) << 9) | (blk >> 3);   // 8 XCDs x 512-slab
  const int z    = swz >> 6;
  const int rest = swz & 63;
  const int y0   = ((rest >> 2) & 15) << 3;
  const int x0   = (rest & 3) << 5;
  const int xl   = tid & 31;
  const int yl   = tid >> 5;

  #pragma unroll
  for (int s = 0; s < 4; ++s) {
    const unsigned q = (unsigned)(s * 256 + tid);
    if (q < (unsigned)TROWS) {
      const unsigned p = q / TX;
      const unsigned r = q - p * TX;
      const unsigned pz = p / TY;
      const int zi = (int)pz, yi = (int)(p - TY * pz);
      const int zz = (z + zi - 1) & (HZ - 1);
      const int yy = (y0 + yi - 1) & (NN - 1);
      const int xg = (x0 - 1 + (int)r) & (NN - 1);
      g2l4(&anat[(zz << 14) | (yy << 7) | xg], &in_t[q]);
    }
  }
  __syncthreads();

  const int base = (yl * TX) + xl;
  const float center = in_t[base + 1 * (TY * TX) + 1 * TX + 1];

  unsigned long long key[NCOL];
  #pragma unroll
  for (int c = 0; c < NCOL; ++c) {
    const int czi = c / 9, cyi = (c / 3) % 3, cxi = c % 3;
    const float v = in_t[base + czi * (TY * TX) + cyi * TX + cxi];
    const unsigned vb = __float_as_uint(v);
    const unsigned db = __float_as_uint(v - center) & 0x7fffffffu;
    const unsigned lo32 = ((unsigned)c << 27) | (vb >> 5);
    key[c] = ((unsigned long long)db << 32) | lo32;
  }

  // Pruned sorting network; CE = f64 min/max pair.
  #pragma unroll
  for (int e = 0; e < NCE; ++e) {
    const int a = NET[e].a, b = NET[e].b;
    const double ka = __builtin_bit_cast(double, key[a]);
    const double kb = __builtin_bit_cast(double, key[b]);
    key[a] = __builtin_bit_cast(unsigned long long, fmin(ka, kb));
    key[b] = __builtin_bit_cast(unsigned long long, fmax(ka, kb));
  }

  // Epilogue: col at [31:27] of low dword, value top-27 bits at [26:0].
  unsigned od[4] = {0, 0, 0, 0};
  unsigned h8 = 0, lo = 0, hi = 0;
  #pragma unroll
  for (int s = 0; s < KSEL; ++s) {
    const unsigned kl = (unsigned)key[s];
    const unsigned c  = (kl >> 27) & 31u;
    const unsigned vbits = (kl & 0x07ffffffu) << 5;
    const unsigned hb = (unsigned)__half_as_ushort(__float2half(__uint_as_float(vbits)));
    if (s < 8) od[s >> 1] |= hb << ((s & 1) * 16);
    else       h8 = hb;
    if (s < 6) lo |= c << (5 * s);
    else       hi |= c << (5 * (s - 6));
  }

  const unsigned vb = (unsigned)((z << 14) | ((y0 + yl) << 7) | (x0 + xl));
  rowsA[vb]   = make_uint4(od[0], od[1], od[2], od[3]);
  rowsB0h[vb] = (unsigned short)h8;
  rowsC[vb]   = make_uint2(lo, hi);
}

// ---------------------------------------------------------------------------
// Pass 2: barrier-free, LDS-free. Per-block halo of rowsA is ~18 KB ->
// L1/L2-resident (XCD swizzle keeps it L2-local). Each thread:
//   - coalesced reads of its own row (uint4 + ushort + uint2 cols)
//   - decodes 9 neighbor voxel ids, gathers 9x(dwordx4 + ushort) from global
//   - sigma/logits/softmax in registers
//   - 9 direct dword stores (wave writes contiguous 1152 B segments)
// No __syncthreads anywhere; occupancy is VGPR-limited only.
// ---------------------------------------------------------------------------
__global__ __launch_bounds__(256, 4) void weights10(
    const uint4* __restrict__ rowsA,
    const unsigned short* __restrict__ rowsB0h,
    const uint2* __restrict__ rowsC,
    const float* __restrict__ ksig,
    float* __restrict__ out) {
  const int tid = threadIdx.x;

  const int blk = blockIdx.x;
  const int swz = ((blk & 7) << 9) | (blk >> 3);
  const int z    = swz >> 6;
  const int rest = swz & 63;
  const int y0   = ((rest >> 2) & 15) << 3;
  const int x0   = (rest & 3) << 5;
  const int xl   = tid & 31;
  const int yl   = tid >> 5;

  const int y = y0 + yl;
  const int x = x0 + xl;
  const unsigned vb_own = (unsigned)((z << 14) | (y << 7) | x);

  // Own row (all coalesced).
  const uint4 a = rowsA[vb_own];
  const unsigned h8o = (unsigned)rowsB0h[vb_own];
  const uint2 cw = rowsC[vb_own];
  const unsigned lo = cw.x, hi = cw.y;

  f16x2 wh[5];
  wh[0] = __builtin_bit_cast(f16x2, a.x);
  wh[1] = __builtin_bit_cast(f16x2, a.y);
  wh[2] = __builtin_bit_cast(f16x2, a.z);
  wh[3] = __builtin_bit_cast(f16x2, a.w);
  wh[4] = __builtin_bit_cast(f16x2, h8o);     // hi half = 0 pad

  // Decode all 9 neighbor voxel ids, then batch-issue all 18 gathers.
  unsigned vbn[KSEL];
  #pragma unroll
  for (int j = 0; j < KSEL; ++j) {
    const unsigned c = (j < 6) ? ((lo >> (5 * j)) & 31u)
                               : ((hi >> (5 * (j - 6))) & 31u);
    const unsigned czi = (c * 57u) >> 9;
    const unsigned rem = c - 9u * czi;
    const unsigned cyi = (rem * 11u) >> 5;
    const unsigned cxi = rem - 3u * cyi;
    const unsigned zz = (unsigned)(z + (int)czi - 1) & (HZ - 1);
    const unsigned yy = (unsigned)(y + (int)cyi - 1) & (NN - 1);
    const unsigned xx = (unsigned)(x + (int)cxi - 1) & (NN - 1);
    vbn[j] = (zz << 14) | (yy << 7) | xx;
  }
  uint4 na[KSEL];
  unsigned nb[KSEL];
  #pragma unroll
  for (int j = 0; j < KSEL; ++j) {
    na[j] = rowsA[vbn[j]];
    nb[j] = (unsigned)rowsB0h[vbn[j]];
  }

  // sigma with ddof=1 (two-pass, matches jnp.std).
  float ws[KSEL];
  #pragma unroll
  for (int l = 0; l < KSEL; ++l) ws[l] = (float)wh[l >> 1][l & 1];
  float mean = 0.f;
  #pragma unroll
  for (int l = 0; l < KSEL; ++l) mean += ws[l];
  mean *= (1.0f / 9.0f);
  float var = 0.f;
  #pragma unroll
  for (int l = 0; l < KSEL; ++l) { const float t = ws[l] - mean; var += t * t; }
  var *= (1.0f / 8.0f);
  const float sigma = sqrtf(var);

  const float ks = ksig[0];
  // log2(e) folded in: e[j] = exp2(logit2[j] - mx2)
  const float inv2 = (sigma == 0.f)
      ? 0.f
      : 1.4426950408889634f / (2.0f * ks * ks * sigma * sigma);

  const _Float16 epsh = (_Float16)1e-6f;
  const f16x2 eps2 = {epsh, epsh};

  float logit[KSEL];
  #pragma unroll
  for (int j = 0; j < KSEL; ++j) {
    const f16x2 nh0 = __builtin_bit_cast(f16x2, na[j].x);
    const f16x2 nh1 = __builtin_bit_cast(f16x2, na[j].y);
    const f16x2 nh2 = __builtin_bit_cast(f16x2, na[j].z);
    const f16x2 nh3 = __builtin_bit_cast(f16x2, na[j].w);
    const f16x2 nh4 = __builtin_bit_cast(f16x2, nb[j]);   // hi half = 0 pad
    float s = 0.f;
    f16x2 dd;
    dd = (wh[0] - nh0) + eps2; s = __builtin_amdgcn_fdot2(dd, dd, s, false);
    dd = (wh[1] - nh1) + eps2; s = __builtin_amdgcn_fdot2(dd, dd, s, false);
    dd = (wh[2] - nh2) + eps2; s = __builtin_amdgcn_fdot2(dd, dd, s, false);
    dd = (wh[3] - nh3) + eps2; s = __builtin_amdgcn_fdot2(dd, dd, s, false);
    dd = (wh[4] - nh4) + eps2; s = __builtin_amdgcn_fdot2(dd, dd, s, false);
    logit[j] = -s * inv2;
  }

  // softmax (exp2 domain) over the 9 logits
  float mx = logit[0];
  #pragma unroll
  for (int j = 1; j < KSEL; ++j) mx = fmaxf(mx, logit[j]);
  float sum = 0.f;
  float e[KSEL];
  #pragma unroll
  for (int j = 0; j < KSEL; ++j) { e[j] = exp2f(logit[j] - mx); sum += e[j]; }
  const float rs = 1.0f / sum;

  // Direct stores: wave writes two contiguous 1152 B segments.
  float* op = out + (size_t)vb_own * 9;
  #pragma unroll
  for (int j = 0; j < KSEL; ++j) op[j] = e[j] * rs;
}

// ---------------------------------------------------------------------------
// d_in: [0] input (P floats), [1] ksigma (1 float), [2] k (int), [3] w (int)
// d_ws: rowsA (16 MB) + rowsB0h (2 MB) + rowsC (8 MB) = 26 MB
// ---------------------------------------------------------------------------
extern "C" void kernel_launch(void* const* d_in, const int* in_sizes, int n_in,
                              void* d_out, int out_size, void* d_ws, size_t ws_size,
                              hipStream_t stream) {
  const float* anat = (const float*)d_in[0];
  const float* ksig = (const float*)d_in[1];
  uint4* rowsA              = (uint4*)d_ws;
  unsigned short* rowsB0h   = (unsigned short*)((char*)d_ws + (size_t)16 * P);
  uint2* rowsC              = (uint2*)((char*)d_ws + (size_t)18 * P);

  const int blocks = P / 256;
  topk10<<<blocks, 256, 0, stream>>>(anat, rowsA, rowsB0h, rowsC);
  weights10<<<blocks, 256, 0, stream>>>(rowsA, rowsB0h, rowsC, ksig, (float*)d_out);
}

// Round 4
// 109.151 us; speedup vs baseline: 1.0654x; 1.0654x over previous
//
#include <hip/hip_runtime.h>
#include <hip/hip_fp16.h>
#include <array>

// Problem constants (reference: H=64, M=N=128, k=9, w=3)
constexpr int HZ   = 64;
constexpr int NN   = 128;
constexpr int P    = HZ * NN * NN;    // 1,048,576 voxels
constexpr int KSEL = 9;
constexpr int NCOL = 27;              // 3x3x3 window

typedef _Float16 f16x2 __attribute__((ext_vector_type(2)));

// ---------------------------------------------------------------------------
// Batcher merge-exchange network for n=27 + backward dead-CE pruning.
// ---------------------------------------------------------------------------
constexpr int compute_nce(int n) {
  int t = 0; while ((1 << t) < n) ++t;
  int cnt = 0;
  for (int p = 1 << (t - 1); p > 0; p >>= 1) {
    int q = 1 << (t - 1), r = 0, d = p;
    while (true) {
      for (int i = 0; i < n - d; ++i)
        if ((i & p) == r) ++cnt;
      if (q == p) break;
      d = q - p; r = p; q >>= 1;
    }
  }
  return cnt;
}
constexpr int NCE_FULL = compute_nce(NCOL);   // 155

struct CEPair { unsigned char a, b; };
constexpr std::array<CEPair, NCE_FULL> make_net() {
  std::array<CEPair, NCE_FULL> net{};
  int t = 0; while ((1 << t) < NCOL) ++t;
  int k = 0;
  for (int p = 1 << (t - 1); p > 0; p >>= 1) {
    int q = 1 << (t - 1), r = 0, d = p;
    while (true) {
      for (int i = 0; i < NCOL - d; ++i)
        if ((i & p) == r) {
          net[k].a = (unsigned char)i;
          net[k].b = (unsigned char)(i + d);
          ++k;
        }
      if (q == p) break;
      d = q - p; r = p; q >>= 1;
    }
  }
  return net;
}
constexpr auto FULLNET = make_net();

constexpr int count_pruned() {
  bool needed[NCOL] = {};
  for (int i = 0; i < KSEL; ++i) needed[i] = true;
  int cnt = 0;
  for (int e = NCE_FULL - 1; e >= 0; --e) {
    const int a = FULLNET[e].a, b = FULLNET[e].b;
    if (needed[a] || needed[b]) { needed[a] = true; needed[b] = true; ++cnt; }
  }
  return cnt;
}
constexpr int NCE = count_pruned();

constexpr std::array<CEPair, NCE> make_pruned() {
  bool needed[NCOL] = {};
  for (int i = 0; i < KSEL; ++i) needed[i] = true;
  std::array<bool, NCE_FULL> keep{};
  for (int e = NCE_FULL - 1; e >= 0; --e) {
    const int a = FULLNET[e].a, b = FULLNET[e].b;
    if (needed[a] || needed[b]) { keep[e] = true; needed[a] = true; needed[b] = true; }
  }
  std::array<CEPair, NCE> out{};
  int k = 0;
  for (int e = 0; e < NCE_FULL; ++e) if (keep[e]) out[k++] = FULLNET[e];
  return out;
}
constexpr auto NET = make_pruned();

// ---------------------------------------------------------------------------
// Async global->LDS DMA helper (16 B wide).
// ---------------------------------------------------------------------------
typedef const __attribute__((address_space(1))) unsigned GU;
typedef __attribute__((address_space(3))) unsigned LU;

__device__ __forceinline__ void g2l16(const void* g, void* l) {
  __builtin_amdgcn_global_load_lds((GU*)g, (LU*)l, 16, 0, 0);
}

// ---------------------------------------------------------------------------
// Pass 1: key = db<<32 | col<<27 | vbits>>5 (63 bits, sign bit 0).
// IEEE order == unsigned order for non-negative doubles, so each CE is
// v_min_f64 + v_max_f64. Order = (db, col) exactly -> exact stable order.
// Input halo staged as a 40-float-wide x-aligned tile so all staging DMA is
// 16 B wide (300 x g2l16 instead of 1020 x g2l4).
// Row output (SoA, 24 B/voxel):
//   rowsA[vb]  = uint4   : halves h0..h7
//   rowsB0[vb] = unsigned: h8 | (hi_cols15 << 16)
//   rowsB1[vb] = unsigned: lo_cols30 (owner-read only)
// ---------------------------------------------------------------------------
constexpr int TXW = 40;               // 16B-aligned staging width
constexpr int TPR = 30;               // 3 z x 10 y halo rows

__global__ __launch_bounds__(256) void topk11(
    const float* __restrict__ anat,
    uint4* __restrict__ rowsA,
    unsigned* __restrict__ rowsB0,
    unsigned* __restrict__ rowsB1) {
  __shared__ float in_t[TPR * TXW];   // 4.8 KB input halo
  const int tid = threadIdx.x;

  const int blk = blockIdx.x;
  const int swz = ((blk & 7) << 9) | (blk >> 3);   // 8 XCDs x 512-slab
  const int z    = swz >> 6;
  const int rest = swz & 63;
  const int y0   = ((rest >> 2) & 15) << 3;
  const int x0   = (rest & 3) << 5;
  const int xl   = tid & 31;
  const int yl   = tid >> 5;

  #pragma unroll
  for (int s = 0; s < 2; ++s) {
    const unsigned q = (unsigned)(s * 256 + tid);
    if (q < 300u) {
      const unsigned p = q / 10u;          // halo row 0..29
      const unsigned t = q - 10u * p;      // 16B group 0..9
      const unsigned zi = p / 10u;
      const unsigned yi = p - 10u * zi;
      const int zz = (z + (int)zi - 1) & (HZ - 1);
      const int yy = (y0 + (int)yi - 1) & (NN - 1);
      const int xb = (x0 - 4 + 4 * (int)t) & (NN - 1);   // group base, 16B aligned
      g2l16(&anat[(zz << 14) | (yy << 7) | xb], &in_t[q * 4]);
    }
  }
  __syncthreads();

  const float center = in_t[(1 * 10 + (yl + 1)) * TXW + 3 + (xl + 1)];

  unsigned long long key[NCOL];
  #pragma unroll
  for (int c = 0; c < NCOL; ++c) {
    const int czi = c / 9, cyi = (c / 3) % 3, cxi = c % 3;
    const float v = in_t[(czi * 10 + (yl + cyi)) * TXW + 3 + xl + cxi];
    const unsigned vb = __float_as_uint(v);
    const unsigned db = __float_as_uint(v - center) & 0x7fffffffu;
    const unsigned lo32 = ((unsigned)c << 27) | (vb >> 5);
    key[c] = ((unsigned long long)db << 32) | lo32;
  }

  // Pruned sorting network; CE = f64 min/max pair.
  #pragma unroll
  for (int e = 0; e < NCE; ++e) {
    const int a = NET[e].a, b = NET[e].b;
    const double ka = __builtin_bit_cast(double, key[a]);
    const double kb = __builtin_bit_cast(double, key[b]);
    key[a] = __builtin_bit_cast(unsigned long long, fmin(ka, kb));
    key[b] = __builtin_bit_cast(unsigned long long, fmax(ka, kb));
  }

  // Epilogue: col at [31:27] of low dword, value top-27 bits at [26:0].
  unsigned od[4] = {0, 0, 0, 0};
  unsigned h8 = 0, lo = 0, hi = 0;
  #pragma unroll
  for (int s = 0; s < KSEL; ++s) {
    const unsigned kl = (unsigned)key[s];
    const unsigned c  = (kl >> 27) & 31u;
    const unsigned vbits = (kl & 0x07ffffffu) << 5;
    const unsigned hb = (unsigned)__half_as_ushort(__float2half(__uint_as_float(vbits)));
    if (s < 8) od[s >> 1] |= hb << ((s & 1) * 16);
    else       h8 = hb;
    if (s < 6) lo |= c << (5 * s);
    else       hi |= c << (5 * (s - 6));
  }

  const unsigned vb = (unsigned)((z << 14) | ((y0 + yl) << 7) | (x0 + xl));
  rowsA[vb]  = make_uint4(od[0], od[1], od[2], od[3]);
  rowsB0[vb] = h8 | (hi << 16);
  rowsB1[vb] = lo;
}

// ---------------------------------------------------------------------------
// Pass 2: 2 z-planes per block (512 voxels / 256 threads) -> staged bytes
// drop from 80 to 53 B per core voxel and barrier count per voxel halves.
// tA halo: 4z x 10y x 34x uint4 rows (g2l16); tB0 halo staged as an
// x-aligned 40-wide dword tile (g2l16, conflict-free stride-4B reads).
// Own lo-cols word read straight from global (coalesced dword).
// LDS 28.2 KB (reused for output staging). All reads from LDS.
// ---------------------------------------------------------------------------
constexpr int WPR  = 40;              // 4z x 10y halo rows
constexpr int WTA  = WPR * 34;        // 1360 uint4 rows in tA
constexpr int WTB  = WPR * TXW;       // 1600 dwords in tB0

__global__ __launch_bounds__(256, 4) void weights11(
    const uint4* __restrict__ rowsA,
    const unsigned* __restrict__ rowsB0,
    const unsigned* __restrict__ rowsB1,
    const float* __restrict__ ksig,
    float* __restrict__ out) {
  __shared__ unsigned lds[WTA * 4 + WTB];   // 5440 + 1600 dw = 28160 B
  unsigned* tA  = lds;
  unsigned* tB0 = lds + WTA * 4;
  const int tid = threadIdx.x;

  const int blk = blockIdx.x;                       // 2048 blocks
  const int swz = ((blk & 7) << 8) | (blk >> 3);    // 8 XCDs x 256-slab
  const int zp   = swz >> 6;                        // z-pair 0..31
  const int rest = swz & 63;
  const int y0   = ((rest >> 2) & 15) << 3;
  const int x0   = (rest & 3) << 5;
  const int xl   = tid & 31;
  const int yl   = tid >> 5;
  const int z0   = zp << 1;

  // Own low-6 col words (coalesced dwords), issued before staging.
  const unsigned vbA = (unsigned)((z0 << 14) | ((y0 + yl) << 7) | (x0 + xl));
  const unsigned low[2] = { rowsB1[vbA], rowsB1[vbA + (1u << 14)] };

  // Stage tA: 1360 uint4 rows.
  #pragma unroll
  for (int s = 0; s < 6; ++s) {
    const unsigned q = (unsigned)(s * 256 + tid);
    if (q < (unsigned)WTA) {
      const unsigned p = q / 34u;
      const unsigned r = q - 34u * p;
      const unsigned zi = p / 10u;
      const unsigned yi = p - 10u * zi;
      const int zz = (z0 + (int)zi - 1) & (HZ - 1);
      const int yy = (y0 + (int)yi - 1) & (NN - 1);
      const int xg = (x0 - 1 + (int)r) & (NN - 1);
      g2l16(&rowsA[(zz << 14) | (yy << 7) | xg], &tA[q * 4]);
    }
  }
  // Stage tB0: 400 x 16B groups (40-wide aligned tile).
  #pragma unroll
  for (int s = 0; s < 2; ++s) {
    const unsigned q = (unsigned)(s * 256 + tid);
    if (q < 400u) {
      const unsigned p = q / 10u;
      const unsigned t = q - 10u * p;
      const unsigned zi = p / 10u;
      const unsigned yi = p - 10u * zi;
      const int zz = (z0 + (int)zi - 1) & (HZ - 1);
      const int yy = (y0 + (int)yi - 1) & (NN - 1);
      const int xb = (x0 - 4 + 4 * (int)t) & (NN - 1);
      g2l16(&rowsB0[(zz << 14) | (yy << 7) | xb], &tB0[q * 4]);
    }
  }
  __syncthreads();

  const float ks = ksig[0];
  const _Float16 epsh = (_Float16)1e-6f;
  const f16x2 eps2 = {epsh, epsh};

  float res[2][9];

  #pragma unroll 2
  for (int vz = 0; vz < 2; ++vz) {
    const unsigned lo = low[vz];
    const int planeO = 1 + vz;                       // own halo z-plane

    // Own row from LDS.
    const int prO = planeO * 10 + (yl + 1);
    const uint4 a = *(const uint4*)&tA[(prO * 34 + (xl + 1)) * 4];
    const unsigned b0 = tB0[prO * TXW + (xl + 4)];
    f16x2 wh[5];
    wh[0] = __builtin_bit_cast(f16x2, a.x);
    wh[1] = __builtin_bit_cast(f16x2, a.y);
    wh[2] = __builtin_bit_cast(f16x2, a.z);
    wh[3] = __builtin_bit_cast(f16x2, a.w);
    wh[4] = __builtin_bit_cast(f16x2, b0 & 0xffffu);   // pad half = 0
    const unsigned hi = b0 >> 16;

    // Decode all 9 neighbor tile addresses, then batch-issue all 18 reads.
    int rA[KSEL], rB[KSEL];
    #pragma unroll
    for (int j = 0; j < KSEL; ++j) {
      const unsigned c = (j < 6) ? ((lo >> (5 * j)) & 31u)
                                 : ((hi >> (5 * (j - 6))) & 31u);
      const unsigned czi = (c * 57u) >> 9;
      const unsigned rem = c - 9u * czi;
      const unsigned cyi = (rem * 11u) >> 5;
      const unsigned cxi = rem - 3u * cyi;
      const int pr = (vz + (int)czi) * 10 + (yl + (int)cyi);
      rA[j] = pr * 34 + (xl + (int)cxi);
      rB[j] = pr * TXW + (xl + (int)cxi + 3);
    }
    uint4 na[KSEL];
    unsigned nb[KSEL];
    #pragma unroll
    for (int j = 0; j < KSEL; ++j) {
      na[j] = *(const uint4*)&tA[rA[j] * 4];
      nb[j] = tB0[rB[j]];
    }

    // sigma with ddof=1 (two-pass, matches jnp.std).
    float ws[KSEL];
    #pragma unroll
    for (int l = 0; l < KSEL; ++l) ws[l] = (float)wh[l >> 1][l & 1];
    float mean = 0.f;
    #pragma unroll
    for (int l = 0; l < KSEL; ++l) mean += ws[l];
    mean *= (1.0f / 9.0f);
    float var = 0.f;
    #pragma unroll
    for (int l = 0; l < KSEL; ++l) { const float t = ws[l] - mean; var += t * t; }
    var *= (1.0f / 8.0f);
    const float sigma = sqrtf(var);

    // log2(e) folded in: e[j] = exp2(logit[j] - mx)
    const float inv2 = (sigma == 0.f)
        ? 0.f
        : 1.4426950408889634f / (2.0f * ks * ks * sigma * sigma);

    float logit[KSEL];
    #pragma unroll
    for (int j = 0; j < KSEL; ++j) {
      const f16x2 nh0 = __builtin_bit_cast(f16x2, na[j].x);
      const f16x2 nh1 = __builtin_bit_cast(f16x2, na[j].y);
      const f16x2 nh2 = __builtin_bit_cast(f16x2, na[j].z);
      const f16x2 nh3 = __builtin_bit_cast(f16x2, na[j].w);
      const f16x2 nh4 = __builtin_bit_cast(f16x2, nb[j] & 0xffffu);
      float s = 0.f;
      f16x2 dd;
      dd = (wh[0] - nh0) + eps2; s = __builtin_amdgcn_fdot2(dd, dd, s, false);
      dd = (wh[1] - nh1) + eps2; s = __builtin_amdgcn_fdot2(dd, dd, s, false);
      dd = (wh[2] - nh2) + eps2; s = __builtin_amdgcn_fdot2(dd, dd, s, false);
      dd = (wh[3] - nh3) + eps2; s = __builtin_amdgcn_fdot2(dd, dd, s, false);
      dd = (wh[4] - nh4) + eps2; s = __builtin_amdgcn_fdot2(dd, dd, s, false);
      logit[j] = -s * inv2;
    }

    // softmax (exp2 domain) over the 9 logits
    float mx = logit[0];
    #pragma unroll
    for (int j = 1; j < KSEL; ++j) mx = fmaxf(mx, logit[j]);
    float sum = 0.f;
    float e[KSEL];
    #pragma unroll
    for (int j = 0; j < KSEL; ++j) { e[j] = exp2f(logit[j] - mx); sum += e[j]; }
    const float rs = 1.0f / sum;
    #pragma unroll
    for (int j = 0; j < KSEL; ++j) res[vz][j] = e[j] * rs;
  }

  // Output staging through LDS -> coalesced float4 stores.
  __syncthreads();
  float* tf = (float*)lds;
  #pragma unroll 2
  for (int vz = 0; vz < 2; ++vz)
    #pragma unroll
    for (int j = 0; j < KSEL; ++j)
      tf[(vz * 256 + tid) * KSEL + j] = res[vz][j];
  __syncthreads();

  const float4* tf4 = (const float4*)lds;
  #pragma unroll
  for (int s = 0; s < 5; ++s) {
    const unsigned q = (unsigned)(s * 256 + tid);
    if (q < 1152u) {
      const unsigned row = q / 72u;            // 16 rows of 32 voxels
      const unsigned f   = q - row * 72u;
      const int zz = z0 + (int)(row >> 3);
      const int yr = (int)(row & 7u);
      const unsigned vb = (unsigned)((zz << 14) | ((y0 + yr) << 7) | x0);
      ((float4*)out)[(size_t)(vb >> 2) * 9 + f] = tf4[row * 72 + f];
    }
  }
}

// ---------------------------------------------------------------------------
// d_in: [0] input (P floats), [1] ksigma (1 float), [2] k (int), [3] w (int)
// d_ws: rowsA (16 MB) + rowsB0 (4 MB) + rowsB1 (4 MB) = 24 MB
// ---------------------------------------------------------------------------
extern "C" void kernel_launch(void* const* d_in, const int* in_sizes, int n_in,
                              void* d_out, int out_size, void* d_ws, size_t ws_size,
                              hipStream_t stream) {
  const float* anat = (const float*)d_in[0];
  const float* ksig = (const float*)d_in[1];
  uint4* rowsA     = (uint4*)d_ws;
  unsigned* rowsB0 = (unsigned*)((char*)d_ws + (size_t)16 * P);
  unsigned* rowsB1 = (unsigned*)((char*)d_ws + (size_t)20 * P);

  topk11<<<P / 256, 256, 0, stream>>>(anat, rowsA, rowsB0, rowsB1);
  weights11<<<P / 512, 256, 0, stream>>>(rowsA, rowsB0, rowsB1, ksig, (float*)d_out);
}

// Round 5
// 105.771 us; speedup vs baseline: 1.0995x; 1.0320x over previous
//
#include <hip/hip_runtime.h>
#include <hip/hip_fp16.h>
#include <array>

// Problem constants (reference: H=64, M=N=128, k=9, w=3)
constexpr int HZ   = 64;
constexpr int NN   = 128;
constexpr int P    = HZ * NN * NN;    // 1,048,576 voxels
constexpr int KSEL = 9;
constexpr int NCOL = 27;              // 3x3x3 window

typedef _Float16 f16x2 __attribute__((ext_vector_type(2)));

// Fused tile geometry: core 4z x 8y x 32x = 1024 voxels per 512-thread block.
constexpr int CZ = 4, CY = 8, CX = 32;
constexpr int RZ = 6, RY = 10, RX = 34;     // row halo (core +1 each side)
constexpr int NROWS = RZ * RY * RX;         // 2040 sorted rows per block
constexpr int IZ = 8, IY = 12, IXW = 40;    // input halo (row halo +1, x 16B-aligned)
constexpr int NIN = IZ * IY * IXW;          // 3840 floats
constexpr int NIN16 = IZ * IY * (IXW / 4);  // 960 16-byte staging groups

// ---------------------------------------------------------------------------
// Batcher merge-exchange network for n=27 + backward dead-CE pruning.
// ---------------------------------------------------------------------------
constexpr int compute_nce(int n) {
  int t = 0; while ((1 << t) < n) ++t;
  int cnt = 0;
  for (int p = 1 << (t - 1); p > 0; p >>= 1) {
    int q = 1 << (t - 1), r = 0, d = p;
    while (true) {
      for (int i = 0; i < n - d; ++i)
        if ((i & p) == r) ++cnt;
      if (q == p) break;
      d = q - p; r = p; q >>= 1;
    }
  }
  return cnt;
}
constexpr int NCE_FULL = compute_nce(NCOL);   // 155

struct CEPair { unsigned char a, b; };
constexpr std::array<CEPair, NCE_FULL> make_net() {
  std::array<CEPair, NCE_FULL> net{};
  int t = 0; while ((1 << t) < NCOL) ++t;
  int k = 0;
  for (int p = 1 << (t - 1); p > 0; p >>= 1) {
    int q = 1 << (t - 1), r = 0, d = p;
    while (true) {
      for (int i = 0; i < NCOL - d; ++i)
        if ((i & p) == r) {
          net[k].a = (unsigned char)i;
          net[k].b = (unsigned char)(i + d);
          ++k;
        }
      if (q == p) break;
      d = q - p; r = p; q >>= 1;
    }
  }
  return net;
}
constexpr auto FULLNET = make_net();

constexpr int count_pruned() {
  bool needed[NCOL] = {};
  for (int i = 0; i < KSEL; ++i) needed[i] = true;
  int cnt = 0;
  for (int e = NCE_FULL - 1; e >= 0; --e) {
    const int a = FULLNET[e].a, b = FULLNET[e].b;
    if (needed[a] || needed[b]) { needed[a] = true; needed[b] = true; ++cnt; }
  }
  return cnt;
}
constexpr int NCE = count_pruned();

constexpr std::array<CEPair, NCE> make_pruned() {
  bool needed[NCOL] = {};
  for (int i = 0; i < KSEL; ++i) needed[i] = true;
  std::array<bool, NCE_FULL> keep{};
  for (int e = NCE_FULL - 1; e >= 0; --e) {
    const int a = FULLNET[e].a, b = FULLNET[e].b;
    if (needed[a] || needed[b]) { keep[e] = true; needed[a] = true; needed[b] = true; }
  }
  std::array<CEPair, NCE> out{};
  int k = 0;
  for (int e = 0; e < NCE_FULL; ++e) if (keep[e]) out[k++] = FULLNET[e];
  return out;
}
constexpr auto NET = make_pruned();

// ---------------------------------------------------------------------------
// Async global->LDS DMA helper (16 B wide, lane-linear dest).
// ---------------------------------------------------------------------------
typedef const __attribute__((address_space(1))) unsigned GU;
typedef __attribute__((address_space(3))) unsigned LU;

__device__ __forceinline__ void g2l16(const void* g, void* l) {
  __builtin_amdgcn_global_load_lds((GU*)g, (LU*)l, 16, 0, 0);
}

// ---------------------------------------------------------------------------
// Fused kernel: per block, sort ALL halo rows (2040) redundantly in-LDS, then
// compute weights for the 1024 core voxels directly from LDS. No intermediate
// global rows array, no second launch.
//
// Sort: key = db<<32 | col<<27 | vbits>>5 (63 bits, sign bit 0). IEEE order ==
// unsigned order for non-negative doubles -> CE = v_min_f64 + v_max_f64.
// Order = (db, col) exactly -> exact NumPy stable order.
//
// LDS layout (dwords):
//   tA  [2040*4] : uint4 per row, halves h0..h7
//   tB0 [2040]   : h8 | (hi_cols15 << 16)
//   tB1 [2040]   : lo_cols30
//   in_t[3840]   : input halo (floats)
// Total 16080 dw = 62.8 KB -> 2 blocks/CU. Output staging reuses tA+tB0.
// ---------------------------------------------------------------------------
__global__ __launch_bounds__(512) void buildk_fused(
    const float* __restrict__ anat,
    const float* __restrict__ ksig,
    float* __restrict__ out) {
  __shared__ unsigned lds[NROWS * 6 + NIN];   // 16080 dwords
  unsigned* tA  = lds;                        // 8160 dw
  unsigned* tB0 = lds + NROWS * 4;            // 2040 dw
  unsigned* tB1 = tB0 + NROWS;                // 2040 dw
  float*    in_t = (float*)(tB1 + NROWS);     // 3840 floats

  const int tid = threadIdx.x;

  // 1024 blocks = 16 zt x 16 yt x 4 xt tiles; XCD-aware swizzle (bijective):
  // zt = (blk&7)*2 + (blk>>9)  -> XCD k owns z in [8k, 8k+8).
  const int blk = blockIdx.x;
  const int swz = ((blk & 7) << 7) | (blk >> 3);
  const int zt   = swz >> 6;
  const int rest = swz & 63;
  const int y0   = ((rest >> 2) & 15) << 3;
  const int x0   = (rest & 3) << 5;
  const int z0   = zt << 2;

  // ---- Stage input halo: 960 x 16B lane-linear DMA ----
  #pragma unroll
  for (int s = 0; s < 2; ++s) {
    const unsigned q = (unsigned)(s * 512 + tid);
    if (q < (unsigned)NIN16) {
      const unsigned p = q / 10u;              // plane-row 0..95
      const unsigned t = q - 10u * p;          // 16B group 0..9
      const unsigned iz = p / 12u;
      const unsigned iy = p - 12u * iz;
      const int zz = (z0 + (int)iz - 2) & (HZ - 1);
      const int yy = (y0 + (int)iy - 2) & (NN - 1);
      const int xb = (x0 - 4 + 4 * (int)t) & (NN - 1);
      g2l16(&anat[(zz << 14) | (yy << 7) | xb], &in_t[q * 4]);
    }
  }
  __syncthreads();

  // ---- Sort phase: 2040 rows, 4 predicated passes of 512 ----
  #pragma unroll 1
  for (int s = 0; s < 4; ++s) {
    const int r = s * 512 + tid;
    if (r < NROWS) {
      const unsigned ru = (unsigned)r;
      const unsigned rz  = ru / (unsigned)(RY * RX);        // /340
      const unsigned rem = ru - (unsigned)(RY * RX) * rz;
      const unsigned ry  = rem / (unsigned)RX;              // /34
      const unsigned rx  = rem - (unsigned)RX * ry;

      const float center = in_t[((rz + 1) * IY + (ry + 1)) * IXW + rx + 3];

      unsigned long long key[NCOL];
      #pragma unroll
      for (int c = 0; c < NCOL; ++c) {
        const int czi = c / 9, cyi = (c / 3) % 3, cxi = c % 3;
        const float v = in_t[((rz + czi) * IY + (ry + cyi)) * IXW + rx + cxi + 2];
        const unsigned vb = __float_as_uint(v);
        const unsigned db = __float_as_uint(v - center) & 0x7fffffffu;
        const unsigned lo32 = ((unsigned)c << 27) | (vb >> 5);
        key[c] = ((unsigned long long)db << 32) | lo32;
      }

      #pragma unroll
      for (int e = 0; e < NCE; ++e) {
        const int a = NET[e].a, b = NET[e].b;
        const double ka = __builtin_bit_cast(double, key[a]);
        const double kb = __builtin_bit_cast(double, key[b]);
        key[a] = __builtin_bit_cast(unsigned long long, fmin(ka, kb));
        key[b] = __builtin_bit_cast(unsigned long long, fmax(ka, kb));
      }

      unsigned od[4] = {0, 0, 0, 0};
      unsigned h8 = 0, lo = 0, hi = 0;
      #pragma unroll
      for (int k = 0; k < KSEL; ++k) {
        const unsigned kl = (unsigned)key[k];
        const unsigned c  = (kl >> 27) & 31u;
        const unsigned vbits = (kl & 0x07ffffffu) << 5;
        const unsigned hb = (unsigned)__half_as_ushort(__float2half(__uint_as_float(vbits)));
        if (k < 8) od[k >> 1] |= hb << ((k & 1) * 16);
        else       h8 = hb;
        if (k < 6) lo |= c << (5 * k);
        else       hi |= c << (5 * (k - 6));
      }

      *(uint4*)&tA[ru * 4] = make_uint4(od[0], od[1], od[2], od[3]);
      tB0[ru] = h8 | (hi << 16);
      tB1[ru] = lo;
    }
  }
  __syncthreads();

  // ---- Weights phase: 2 core voxels per thread ----
  const int xl = tid & 31;
  const int yl = (tid >> 5) & 7;
  const int zl = tid >> 8;                    // 0..1

  const float ks = ksig[0];
  const _Float16 epsh = (_Float16)1e-6f;
  const f16x2 eps2 = {epsh, epsh};

  float res[2][9];

  #pragma unroll 2
  for (int vz = 0; vz < 2; ++vz) {
    const int zv = 2 * zl + vz;               // core z offset 0..3

    const int rho_own = ((zv + 1) * RY + (yl + 1)) * RX + (xl + 1);
    const uint4 a = *(const uint4*)&tA[rho_own * 4];
    const unsigned b0 = tB0[rho_own];
    const unsigned lo = tB1[rho_own];
    f16x2 wh[5];
    wh[0] = __builtin_bit_cast(f16x2, a.x);
    wh[1] = __builtin_bit_cast(f16x2, a.y);
    wh[2] = __builtin_bit_cast(f16x2, a.z);
    wh[3] = __builtin_bit_cast(f16x2, a.w);
    wh[4] = __builtin_bit_cast(f16x2, b0 & 0xffffu);   // pad half = 0
    const unsigned hi = b0 >> 16;

    // Decode all 9 neighbor row addresses, then batch-issue all 18 reads.
    int rho[KSEL];
    #pragma unroll
    for (int j = 0; j < KSEL; ++j) {
      const unsigned c = (j < 6) ? ((lo >> (5 * j)) & 31u)
                                 : ((hi >> (5 * (j - 6))) & 31u);
      const unsigned czi = (c * 57u) >> 9;
      const unsigned rem = c - 9u * czi;
      const unsigned cyi = (rem * 11u) >> 5;
      const unsigned cxi = rem - 3u * cyi;
      rho[j] = ((zv + (int)czi) * RY + (yl + (int)cyi)) * RX + (xl + (int)cxi);
    }
    uint4 na[KSEL];
    unsigned nb[KSEL];
    #pragma unroll
    for (int j = 0; j < KSEL; ++j) {
      na[j] = *(const uint4*)&tA[rho[j] * 4];
      nb[j] = tB0[rho[j]];
    }

    // sigma with ddof=1 (two-pass, matches jnp.std).
    float ws[KSEL];
    #pragma unroll
    for (int l = 0; l < KSEL; ++l) ws[l] = (float)wh[l >> 1][l & 1];
    float mean = 0.f;
    #pragma unroll
    for (int l = 0; l < KSEL; ++l) mean += ws[l];
    mean *= (1.0f / 9.0f);
    float var = 0.f;
    #pragma unroll
    for (int l = 0; l < KSEL; ++l) { const float t = ws[l] - mean; var += t * t; }
    var *= (1.0f / 8.0f);
    const float sigma = sqrtf(var);

    // log2(e) folded in: e[j] = exp2(logit[j] - mx)
    const float inv2 = (sigma == 0.f)
        ? 0.f
        : 1.4426950408889634f / (2.0f * ks * ks * sigma * sigma);

    float logit[KSEL];
    #pragma unroll
    for (int j = 0; j < KSEL; ++j) {
      const f16x2 nh0 = __builtin_bit_cast(f16x2, na[j].x);
      const f16x2 nh1 = __builtin_bit_cast(f16x2, na[j].y);
      const f16x2 nh2 = __builtin_bit_cast(f16x2, na[j].z);
      const f16x2 nh3 = __builtin_bit_cast(f16x2, na[j].w);
      const f16x2 nh4 = __builtin_bit_cast(f16x2, nb[j] & 0xffffu);
      float s = 0.f;
      f16x2 dd;
      dd = (wh[0] - nh0) + eps2; s = __builtin_amdgcn_fdot2(dd, dd, s, false);
      dd = (wh[1] - nh1) + eps2; s = __builtin_amdgcn_fdot2(dd, dd, s, false);
      dd = (wh[2] - nh2) + eps2; s = __builtin_amdgcn_fdot2(dd, dd, s, false);
      dd = (wh[3] - nh3) + eps2; s = __builtin_amdgcn_fdot2(dd, dd, s, false);
      dd = (wh[4] - nh4) + eps2; s = __builtin_amdgcn_fdot2(dd, dd, s, false);
      logit[j] = -s * inv2;
    }

    // softmax (exp2 domain) over the 9 logits
    float mx = logit[0];
    #pragma unroll
    for (int j = 1; j < KSEL; ++j) mx = fmaxf(mx, logit[j]);
    float sum = 0.f;
    float e[KSEL];
    #pragma unroll
    for (int j = 0; j < KSEL; ++j) { e[j] = exp2f(logit[j] - mx); sum += e[j]; }
    const float rs = 1.0f / sum;
    #pragma unroll
    for (int j = 0; j < KSEL; ++j) res[vz][j] = e[j] * rs;
  }

  // ---- Output staging through LDS -> coalesced float4 stores ----
  __syncthreads();                            // rows LDS now dead
  float* tf = (float*)lds;                    // 9216 floats < tA+tB0 region
  #pragma unroll 2
  for (int vz = 0; vz < 2; ++vz) {
    const int zv = 2 * zl + vz;
    const int pos = (zv << 8) + (yl << 5) + xl;   // zv-major staging order
    #pragma unroll
    for (int j = 0; j < KSEL; ++j) tf[pos * KSEL + j] = res[vz][j];
  }
  __syncthreads();

  const float4* tf4 = (const float4*)lds;
  #pragma unroll
  for (int s = 0; s < 5; ++s) {
    const unsigned q = (unsigned)(s * 512 + tid);
    if (q < 2304u) {
      const unsigned row = q / 72u;            // 32 (z,y) rows of 32 voxels
      const unsigned f   = q - row * 72u;
      const int zz = z0 + (int)(row >> 3);
      const int yr = (int)(row & 7u);
      const unsigned vb = (unsigned)((zz << 14) | ((y0 + yr) << 7) | x0);
      ((float4*)out)[(size_t)(vb >> 2) * 9 + f] = tf4[row * 72 + f];
    }
  }
}

// ---------------------------------------------------------------------------
// d_in: [0] input (P floats), [1] ksigma (1 float), [2] k (int), [3] w (int)
// d_ws: unused (fully fused).
// ---------------------------------------------------------------------------
extern "C" void kernel_launch(void* const* d_in, const int* in_sizes, int n_in,
                              void* d_out, int out_size, void* d_ws, size_t ws_size,
                              hipStream_t stream) {
  const float* anat = (const float*)d_in[0];
  const float* ksig = (const float*)d_in[1];
  buildk_fused<<<P / (CZ * CY * CX), 512, 0, stream>>>(anat, ksig, (float*)d_out);
}